// Round 14
// baseline (1515.193 us; speedup 1.0000x reference)
//
#include <hip/hip_runtime.h>

// Problem constants (from reference)
constexpr int B_ = 16, T_ = 128, S_ = 128;
constexpr int ROWS = B_ * S_;        // 2048
constexpr int NSTEPS = T_ - 1;       // 127
constexpr int TPRED = 20;
constexpr int TOUT = NSTEPS - TPRED; // 107
constexpr int TB = 512;              // 8 waves
constexpr int NBLK = 256;            // 128 A (64pr x 2cell) + 128 B (64pr x 2 col-halves)

// ws layout in 4-byte units. Zero region contiguous [0, ZERO_DW).
constexpr int OFF_HN = 0;                       // [2][2048][64] f16 (parity = t&1)
constexpr int OFF_HS = OFF_HN + 131072;
constexpr int OFF_HD = OFF_HS + 131072;         // [2][2048][128] f16
constexpr int OFF_CN = OFF_HD + 262144;         // cn lane-order [64pr][2tl][4sub][64][4]
constexpr int OFF_CS = OFF_CN + 131072;
constexpr int OFF_CD = OFF_CS + 131072;         // cd lane-order [64pr][2ch][2tl][4sub][64][4]
constexpr int OFF_GP = OFF_CD + 262144;         // gpart[2][64pr][2cell][8ct][4g][2tl][256]
constexpr int GP_DW = 2 * 64 * 2 * 8 * 4 * 2 * 256;   // 4194304 (r13 bug: was half)
constexpr int OFF_OUTS = OFF_GP + GP_DW;        // outs[127][2048][2] f32 (atomicAdd)
constexpr int ZERO_DW = OFF_OUTS + NSTEPS * ROWS * 2;
// packed fp16 weight fragments (same format as r6/r11)
constexpr int OFF_NPK = ZERO_DW;
constexpr int NPK_DW = 16 * 7 * 256;            // 28672
constexpr int OFF_SPK = OFF_NPK + NPK_DW;
constexpr int OFF_DPK = OFF_SPK + NPK_DW;       // 32 nt * 16 tiles * 256 dw
constexpr int DPK_DW = 32 * 16 * 256;
constexpr int PACK_DWORDS = 2 * NPK_DW + DPK_DW;

typedef _Float16 half8 __attribute__((ext_vector_type(8)));
typedef float float4v __attribute__((ext_vector_type(4)));

__device__ __forceinline__ float sigm(float x) { return 1.f / (1.f + __expf(-x)); }
__device__ __forceinline__ float tanh_(float x) { return 2.f / (1.f + __expf(-2.f * x)) - 1.f; }
__device__ __forceinline__ unsigned int pack2(float a, float b) {
    union { unsigned int u; _Float16 h[2]; } x;
    x.h[0] = (_Float16)a; x.h[1] = (_Float16)b; return x.u;
}

// ---- pack fp32 weights into MFMA B-fragment tiles (fp16), once per call ----
// B-frag 16x16x32: lane l holds B[k=(l>>4)*8+j][n=l&15] -> tile = 512 f16 = 256 dw.
// n/s packs per nt(16): [Wh kt0, Wh kt1, Wa kt0, Wa kt1, Wb kt0, Wb kt1, Xaug]
// d pack per nt(32): [dWx kt0..3, dWh kt0..3, dWa kt0..3, dWb kt0..3]
__global__ __launch_bounds__(256) void pack_weights(
    const float* __restrict__ nWx, const float* __restrict__ nWh,
    const float* __restrict__ nWa, const float* __restrict__ nWb, const float* __restrict__ nb,
    const float* __restrict__ sWx, const float* __restrict__ sWh,
    const float* __restrict__ sWa, const float* __restrict__ sWb, const float* __restrict__ sb,
    const float* __restrict__ dWx, const float* __restrict__ dWh,
    const float* __restrict__ dWa, const float* __restrict__ dWb,
    unsigned int* __restrict__ wsu)
{
    int idx = blockIdx.x * 256 + threadIdx.x;
    if (idx >= PACK_DWORDS) return;
    if (idx < 2 * NPK_DW) {
        bool isS = idx >= NPK_DW;
        int dn = isS ? idx - NPK_DW : idx;
        int tile = dn >> 8;
        int e = (dn & 255) * 2;
        int lane = e >> 3, j0 = e & 7;
        int quad = lane >> 4;
        int nt = tile / 7, tt = tile % 7;
        int col = nt * 16 + (lane & 15);
        float v0, v1;
        if (tt < 6) {
            const float* W = isS ? ((tt < 2) ? sWh : (tt < 4) ? sWa : sWb)
                                 : ((tt < 2) ? nWh : (tt < 4) ? nWa : nWb);
            int k = (tt & 1) * 32 + quad * 8 + j0;
            v0 = W[k * 256 + col]; v1 = W[(k + 1) * 256 + col];
        } else {
            int kl = quad * 8 + j0;
            auto xv = [&](int k) -> float {
                if (!isS) { if (k < 3) return nWx[k * 256 + col]; if (k == 3) return nb[col]; return 0.f; }
                else      { if (k == 4) return sWx[col]; if (k == 5) return sb[col]; return 0.f; }
            };
            v0 = xv(kl); v1 = xv(kl + 1);
        }
        wsu[(isS ? OFF_SPK : OFF_NPK) + dn] = pack2(v0, v1);
    } else {
        int dd = idx - 2 * NPK_DW;
        int tile = dd >> 8;
        int e = (dd & 255) * 2;
        int lane = e >> 3, j0 = e & 7;
        int quad = lane >> 4;
        int nt = tile >> 4, tt = tile & 15;
        const float* W = (tt < 4) ? dWx : (tt < 8) ? dWh : (tt < 12) ? dWa : dWb;
        int k = (tt & 3) * 32 + quad * 8 + j0;
        int col = nt * 16 + (lane & 15);
        wsu[OFF_DPK + dd] = pack2(W[k * 512 + col], W[(k + 1) * 512 + col]);
    }
}

// Launch li: A blocks (0-127) = step t=li, one cell per block, 32 rows: cell GEMM +
// its cell-half of dWx@dec -> gpart. B blocks (128-255) = step t=li-1, 64-col half
// of d-cell from gpart(cell0)+gpart(cell1)+dWh/dWa/dWb. Hand-offs cross-launch.
__global__ __launch_bounds__(TB) void pipe_kernel(
    int li,
    const float* __restrict__ input,
    const float* __restrict__ db,
    const float* __restrict__ onW, const float* __restrict__ osW,
    float* __restrict__ ws)
{
    const int tid = threadIdx.x;
    const int wave = tid >> 6, lane = tid & 63;
    const int quad = lane >> 4, l15 = lane & 15;
    const int blk = blockIdx.x;

    _Float16* hnG = (_Float16*)((unsigned int*)ws + OFF_HN);
    _Float16* hsG = (_Float16*)((unsigned int*)ws + OFF_HS);
    _Float16* hdG = (_Float16*)((unsigned int*)ws + OFF_HD);
    float* gpart = ws + OFF_GP;
    float* outs = ws + OFF_OUTS;
    const _Float16* pd = (const _Float16*)((const unsigned int*)ws + OFF_DPK);

    __shared__ __align__(16) _Float16 sh_h[34 * 72];     // A: own cell h (+halo)
    __shared__ __align__(16) _Float16 sh_xa[32 * 40];    // A: x_aug
    __shared__ __align__(16) _Float16 sh_dh[32 * 72];    // A: own cell h-new (dec half)
    __shared__ __align__(16) _Float16 sh_hd[34 * 136];   // B: hd(t-1) (+halo)
    __shared__ float sh_hdnew[32 * 64];                  // B: own col-half of hd(t)

    if (blk < 128) {
        // ================= A role: step t = li, cell = blk&1, 32 rows =================
        if (li > 126) return;
        const int pr = blk >> 1, cell = blk & 1;
        const int r0 = pr * 32;
        const int b = r0 >> 7;
        const int s0 = r0 & 127;
        const bool leftOK = (pr & 3) != 0;
        const bool rightOK = (pr & 3) != 3;
        const int pin = (li + 1) & 1, pout = li & 1;
        const _Float16* hC = (cell ? hsG : hnG) + (size_t)pin * ROWS * 64;
        _Float16* hN = (cell ? hsG : hnG) + (size_t)pout * ROWS * 64;
        float* cB = ws + (cell ? OFF_CS : OFF_CN);

        for (int i = tid; i < 1088; i += TB) {
            int row = i >> 5, p = i & 31;
            int grow = r0 + row - 1;
            bool v = (row == 0) ? leftOK : ((row == 33) ? rightOK : true);
            unsigned int val = v ? ((const unsigned int*)hC)[(size_t)grow * 32 + p] : 0u;
            *(unsigned int*)(sh_h + row * 72 + 2 * p) = val;
        }
        for (int i = tid; i < 544; i += TB) {
            int r = i / 17, d = 3 + (i % 17);
            ((unsigned int*)sh_xa)[r * 20 + d] = 0u;
        }
        if (tid < 32) {
            const float* xp = input + ((size_t)(b * T_ + li) * S_ + (s0 + tid)) * 4;
            unsigned int* row = (unsigned int*)sh_xa + tid * 20;
            row[0] = pack2(xp[0], xp[1]);
            row[1] = pack2(xp[2], 1.f);
            row[2] = pack2(xp[3], 1.f);
        }
        __syncthreads();

        // cell GEMM: wave -> tl = wave>>2 (row-tile), sub = wave&3 (16-col sub)
        const int tl = wave >> 2, sub = wave & 3;
        {
            const _Float16* pk = (const _Float16*)((const unsigned int*)ws + (cell ? OFF_SPK : OFF_NPK));
            const int rb = 1 + tl * 16 + l15;
            half8 ah0 = *(const half8*)(sh_h + rb * 72 + quad * 8);
            half8 ah1 = *(const half8*)(sh_h + rb * 72 + 32 + quad * 8);
            half8 aa0 = *(const half8*)(sh_h + (rb + 1) * 72 + quad * 8);
            half8 aa1 = *(const half8*)(sh_h + (rb + 1) * 72 + 32 + quad * 8);
            half8 ab0 = *(const half8*)(sh_h + (rb - 1) * 72 + quad * 8);
            half8 ab1 = *(const half8*)(sh_h + (rb - 1) * 72 + 32 + quad * 8);
            half8 ax  = *(const half8*)(sh_xa + (tl * 16 + l15) * 40 + quad * 8);
            float4v acc[4];
#pragma unroll
            for (int g = 0; g < 4; ++g) acc[g] = (float4v){0.f, 0.f, 0.f, 0.f};
#pragma unroll
            for (int g = 0; g < 4; ++g) {
                const _Float16* base = pk + (size_t)(4 * g + sub) * 7 * 512 + lane * 8;
                acc[g] = __builtin_amdgcn_mfma_f32_16x16x32_f16(ah0, *(const half8*)(base),        acc[g], 0, 0, 0);
                acc[g] = __builtin_amdgcn_mfma_f32_16x16x32_f16(ah1, *(const half8*)(base + 512),  acc[g], 0, 0, 0);
                acc[g] = __builtin_amdgcn_mfma_f32_16x16x32_f16(aa0, *(const half8*)(base + 1024), acc[g], 0, 0, 0);
                acc[g] = __builtin_amdgcn_mfma_f32_16x16x32_f16(aa1, *(const half8*)(base + 1536), acc[g], 0, 0, 0);
                acc[g] = __builtin_amdgcn_mfma_f32_16x16x32_f16(ab0, *(const half8*)(base + 2048), acc[g], 0, 0, 0);
                acc[g] = __builtin_amdgcn_mfma_f32_16x16x32_f16(ab1, *(const half8*)(base + 2560), acc[g], 0, 0, 0);
                acc[g] = __builtin_amdgcn_mfma_f32_16x16x32_f16(ax,  *(const half8*)(base + 3072), acc[g], 0, 0, 0);
            }
            size_t cIdx = ((size_t)((pr * 2 + tl) * 4 + sub) * 64 + lane) * 4;
            float4v cold = *(const float4v*)(cB + cIdx);
            float4v cnew;
            const int kcol = 16 * sub + l15;
#pragma unroll
            for (int r = 0; r < 4; ++r) {
                float c2 = sigm(acc[1][r]) * cold[r] + sigm(acc[0][r]) * tanh_(acc[2][r]);
                float h2 = sigm(acc[3][r]) * tanh_(c2);
                cnew[r] = c2;
                int row = tl * 16 + quad * 4 + r;
                hN[(size_t)(r0 + row) * 64 + kcol] = (_Float16)h2;
                sh_dh[row * 72 + kcol] = (_Float16)h2;
            }
            *(float4v*)(cB + cIdx) = cnew;
        }
        __syncthreads();

        // dWx cell-half partials: wave = ct (16-col tile of 128 d-cols)
        {
            const int ct = wave;
            half8 aD[2][2];   // [tl][ktl]
#pragma unroll
            for (int t2 = 0; t2 < 2; ++t2)
#pragma unroll
                for (int ktl = 0; ktl < 2; ++ktl)
                    aD[t2][ktl] = *(const half8*)(sh_dh + (t2 * 16 + l15) * 72 + ktl * 32 + quad * 8);
            float* gp = gpart + ((((size_t)(li & 1) * 64 + pr) * 2 + cell) * 8 + ct) * (4 * 2 * 256);
#pragma unroll
            for (int g = 0; g < 4; ++g) {
                const _Float16* base = pd + ((size_t)(g * 8 + ct) * 16 + 2 * cell) * 512 + lane * 8;
                half8 b0 = *(const half8*)(base);
                half8 b1 = *(const half8*)(base + 512);
#pragma unroll
                for (int t2 = 0; t2 < 2; ++t2) {
                    float4v acc = (float4v){0.f, 0.f, 0.f, 0.f};
                    acc = __builtin_amdgcn_mfma_f32_16x16x32_f16(aD[t2][0], b0, acc, 0, 0, 0);
                    acc = __builtin_amdgcn_mfma_f32_16x16x32_f16(aD[t2][1], b1, acc, 0, 0, 0);
                    *(float4v*)&gp[(g * 2 + t2) * 256 + lane * 4] = acc;
                }
            }
        }
    } else {
        // ============ B role: step t = li-1, col-half ch, 32 rows ============
        if (li < 1) return;
        const int bb = blk - 128;
        const int pr = bb >> 1, ch = bb & 1;
        const int t = li - 1;
        const int r0 = pr * 32;
        const bool leftOK = (pr & 3) != 0;
        const bool rightOK = (pr & 3) != 3;
        const int pinD = li & 1;            // hd(t-1) parity
        const int poutD = (li + 1) & 1;     // hd(t) parity
        const _Float16* hdC = hdG + (size_t)pinD * ROWS * 128;
        _Float16* hdN = hdG + (size_t)poutD * ROWS * 128;
        float* cd = ws + OFF_CD;

        for (int i = tid; i < 2176; i += TB) {
            int row = i >> 6, p = i & 63;
            int grow = r0 + row - 1;
            bool v = (row == 0) ? leftOK : ((row == 33) ? rightOK : true);
            unsigned int val = v ? ((const unsigned int*)hdC)[(size_t)grow * 64 + p] : 0u;
            *(unsigned int*)(sh_hd + row * 136 + 2 * p) = val;
        }
        __syncthreads();

        // wave: tl = wave>>2, sub = wave&3; own 16-col tile ct2 = ch*4+sub
        const int tl = wave >> 2, sub = wave & 3;
        const int ct2 = ch * 4 + sub;
        const int par = (li + 1) & 1;       // gpart parity written by A at launch li-1
        const float* gp0 = gpart + ((((size_t)par * 64 + pr) * 2 + 0) * 8 + ct2) * (4 * 2 * 256);
        const float* gp1 = gpart + ((((size_t)par * 64 + pr) * 2 + 1) * 8 + ct2) * (4 * 2 * 256);
        float4v acc[4];
#pragma unroll
        for (int g = 0; g < 4; ++g)
            acc[g] = *(const float4v*)&gp0[(g * 2 + tl) * 256 + lane * 4]
                   + *(const float4v*)&gp1[(g * 2 + tl) * 256 + lane * 4];
        const int rb = 1 + tl * 16 + l15;
        half8 aH[4], aA[4], aB4[4];
#pragma unroll
        for (int kt = 0; kt < 4; ++kt) {
            aH[kt]  = *(const half8*)(sh_hd + rb * 136 + kt * 32 + quad * 8);
            aA[kt]  = *(const half8*)(sh_hd + (rb + 1) * 136 + kt * 32 + quad * 8);
            aB4[kt] = *(const half8*)(sh_hd + (rb - 1) * 136 + kt * 32 + quad * 8);
        }
#pragma unroll
        for (int g = 0; g < 4; ++g) {
            const _Float16* base = pd + (size_t)(g * 8 + ct2) * 16 * 512 + lane * 8;
#pragma unroll
            for (int kt = 0; kt < 4; ++kt)
                acc[g] = __builtin_amdgcn_mfma_f32_16x16x32_f16(aH[kt],  *(const half8*)(base + (4 + kt) * 512),  acc[g], 0, 0, 0);
#pragma unroll
            for (int kt = 0; kt < 4; ++kt)
                acc[g] = __builtin_amdgcn_mfma_f32_16x16x32_f16(aA[kt],  *(const half8*)(base + (8 + kt) * 512),  acc[g], 0, 0, 0);
#pragma unroll
            for (int kt = 0; kt < 4; ++kt)
                acc[g] = __builtin_amdgcn_mfma_f32_16x16x32_f16(aB4[kt], *(const half8*)(base + (12 + kt) * 512), acc[g], 0, 0, 0);
        }
        // LSTM epilogue; cd in-place; persist own col-half of hd(t)
        const int kd = ct2 * 16 + l15;
        float bi = db[kd], bf = db[128 + kd], bu = db[256 + kd], bo = db[384 + kd];
        float* cPtr = cd + ((size_t)(((pr * 2 + ch) * 2 + tl) * 4 + sub) * 64 + lane) * 4;
        float4v cold = *(float4v*)cPtr, cnew;
#pragma unroll
        for (int r = 0; r < 4; ++r) {
            float c2 = sigm(acc[1][r] + bf) * cold[r] + sigm(acc[0][r] + bi) * tanh_(acc[2][r] + bu);
            float h2 = sigm(acc[3][r] + bo) * tanh_(c2);
            cnew[r] = c2;
            int row = tl * 16 + quad * 4 + r;
            hdN[(size_t)(r0 + row) * 128 + kd] = (_Float16)h2;
            sh_hdnew[row * 64 + sub * 16 + l15] = h2;
        }
        *(float4v*)cPtr = cnew;
        __syncthreads();

        // heads: 32 rows x 2 heads x 8 lanes; partial over own 64 cols -> atomicAdd
        {
            int p = tid >> 3, l8 = tid & 7;
            int row = p >> 1, head = p & 1;
            const float* W = (head ? osW : onW) + ch * 64;
            float partial = 0.f;
#pragma unroll
            for (int k = 0; k < 64; k += 8) partial += sh_hdnew[row * 64 + k + l8] * W[k + l8];
#pragma unroll
            for (int off = 4; off; off >>= 1) partial += __shfl_down(partial, off, 8);
            if (l8 == 0) atomicAdd(&outs[((size_t)t * ROWS + (r0 + row)) * 2 + head], partial);
        }
    }
}

// Assemble data outputs for t in [20,126]; head biases applied here.
__global__ __launch_bounds__(256) void assemble_kernel(
    const float* __restrict__ input, const float* __restrict__ ws,
    const float* __restrict__ onb, const float* __restrict__ osb,
    float* __restrict__ out)
{
    const float* outs = ws + OFF_OUTS;
    int idx = blockIdx.x * 256 + threadIdx.x;  // (b, tt, s)
    if (idx >= B_ * TOUT * S_) return;
    int s = idx & 127;
    int tmp = idx >> 7;
    int tt = tmp % TOUT;
    int b = tmp / TOUT;
    int t = tt + TPRED;
    int row = b * S_ + s;
    float ob0 = onb[0], ob1 = osb[0];
    float o0 = outs[((size_t)t * ROWS + row) * 2 + 0] + ob0;
    float o1 = outs[((size_t)t * ROWS + row) * 2 + 1] + ob1;
    float inflow = (s == 0) ? input[(((size_t)b * T_ + (t + 1)) * S_ + 0) * 4 + 1]
                            : (outs[((size_t)t * ROWS + row - 1) * 2 + 0] + ob0);
    float numc = input[(((size_t)b * T_ + t) * S_ + s) * 4 + 2] + inflow - o0;
    float spd = (s == 0) ? input[(((size_t)b * T_ + (t + 1)) * S_ + 0) * 4 + 3] : o1;
    float4 v = make_float4(o0, inflow, numc, spd);
    reinterpret_cast<float4*>(out)[idx] = v;
}

extern "C" void kernel_launch(void* const* d_in, const int* in_sizes, int n_in,
                              void* d_out, int out_size, void* d_ws, size_t ws_size,
                              hipStream_t stream) {
    const float* input = (const float*)d_in[0];
    const float* nWx = (const float*)d_in[1];
    const float* nWh = (const float*)d_in[2];
    const float* nWa = (const float*)d_in[3];
    const float* nWb = (const float*)d_in[4];
    const float* nb  = (const float*)d_in[5];
    const float* sWx = (const float*)d_in[6];
    const float* sWh = (const float*)d_in[7];
    const float* sWa = (const float*)d_in[8];
    const float* sWb = (const float*)d_in[9];
    const float* sb  = (const float*)d_in[10];
    const float* dWx = (const float*)d_in[11];
    const float* dWh = (const float*)d_in[12];
    const float* dWa = (const float*)d_in[13];
    const float* dWb = (const float*)d_in[14];
    const float* db  = (const float*)d_in[15];
    const float* onW = (const float*)d_in[16];
    const float* onb = (const float*)d_in[17];
    const float* osW = (const float*)d_in[18];
    const float* osb = (const float*)d_in[19];

    float* ws = (float*)d_ws;

    // zero h (both parities) + c + gpart + outs
    hipMemsetAsync(ws, 0, (size_t)ZERO_DW * 4, stream);

    // pack weights into MFMA B-fragment tiles (once per call)
    pack_weights<<<dim3((PACK_DWORDS + 255) / 256), dim3(256), 0, stream>>>(
        nWx, nWh, nWa, nWb, nb, sWx, sWh, sWa, sWb, sb,
        dWx, dWh, dWa, dWb, (unsigned int*)ws);

    // pipelined launches: li=0 (A only) .. li=127 (B only)
    for (int li = 0; li <= NSTEPS; ++li) {
        pipe_kernel<<<dim3(NBLK), dim3(TB), 0, stream>>>(
            li, input, db, onW, osW, ws);
    }

    int nout = B_ * TOUT * S_;
    assemble_kernel<<<dim3((nout + 255) / 256), dim3(256), 0, stream>>>(
        input, ws, onb, osb, (float*)d_out);
}

// Round 15
// 1231.627 us; speedup vs baseline: 1.2302x; 1.2302x over previous
//
#include <hip/hip_runtime.h>

// Problem constants (from reference)
constexpr int B_ = 16, T_ = 128, S_ = 128;
constexpr int ROWS = B_ * S_;        // 2048
constexpr int NSTEPS = T_ - 1;       // 127
constexpr int TPRED = 20;
constexpr int TOUT = NSTEPS - TPRED; // 107
constexpr int RPB = 16;              // rows per row-tile (MFMA M)
constexpr int TB = 512;              // 8 waves
constexpr int NBLK = 256;            // 128 A-role + 128 B-role blocks

// ws layout in 4-byte units.
constexpr int OFF_HN = 0;                       // [2][2048][64] f16 (parity = step&1)
constexpr int OFF_HS = OFF_HN + 131072;
constexpr int OFF_HD = OFF_HS + 131072;         // [2][2048][128] f16
constexpr int OFF_CN = OFF_HD + 262144;         // cn[128*4][64][4] f32 (A-block in-place)
constexpr int OFF_CS = OFF_CN + 131072;
constexpr int OFF_CD = OFF_CS + 131072;         // cd[128*8][64][4] f32 (B-block in-place)
constexpr int OFF_GP = OFF_CD + 262144;         // gpart[2][128][8][4][64][4] f32
constexpr int OFF_OUTS = OFF_GP + 2097152;      // outs[127][2048][2] f32
constexpr int ZERO_DW = OFF_GP;                 // zero h + c only
// packed fp16 weight fragments (same format as r6)
constexpr int OFF_NPK = OFF_OUTS + NSTEPS * ROWS * 2;
constexpr int NPK_DW = 16 * 7 * 256;            // 28672
constexpr int OFF_SPK = OFF_NPK + NPK_DW;
constexpr int OFF_DPK = OFF_SPK + NPK_DW;       // 32 nt * 16 tiles * 256 dw
constexpr int DPK_DW = 32 * 16 * 256;           // 131072
constexpr int PACK_DWORDS = 2 * NPK_DW + DPK_DW;

typedef _Float16 half8 __attribute__((ext_vector_type(8)));
typedef float float4v __attribute__((ext_vector_type(4)));

__device__ __forceinline__ float sigm(float x) { return 1.f / (1.f + __expf(-x)); }
__device__ __forceinline__ float tanh_(float x) { return 2.f / (1.f + __expf(-2.f * x)) - 1.f; }
__device__ __forceinline__ unsigned int pack2(float a, float b) {
    union { unsigned int u; _Float16 h[2]; } x;
    x.h[0] = (_Float16)a; x.h[1] = (_Float16)b; return x.u;
}

// ---- pack fp32 weights into MFMA B-fragment tiles (fp16), once per call ----
// B-frag 16x16x32: lane l holds B[k=(l>>4)*8+j][n=l&15] -> tile = 512 f16 = 256 dw.
// n/s packs per nt(16): [Wh kt0, Wh kt1, Wa kt0, Wa kt1, Wb kt0, Wb kt1, Xaug]
// d pack per nt(32): [dWx kt0..3, dWh kt0..3, dWa kt0..3, dWb kt0..3]
__global__ __launch_bounds__(256) void pack_weights(
    const float* __restrict__ nWx, const float* __restrict__ nWh,
    const float* __restrict__ nWa, const float* __restrict__ nWb, const float* __restrict__ nb,
    const float* __restrict__ sWx, const float* __restrict__ sWh,
    const float* __restrict__ sWa, const float* __restrict__ sWb, const float* __restrict__ sb,
    const float* __restrict__ dWx, const float* __restrict__ dWh,
    const float* __restrict__ dWa, const float* __restrict__ dWb,
    unsigned int* __restrict__ wsu)
{
    int idx = blockIdx.x * 256 + threadIdx.x;
    if (idx >= PACK_DWORDS) return;
    if (idx < 2 * NPK_DW) {
        bool isS = idx >= NPK_DW;
        int dn = isS ? idx - NPK_DW : idx;
        int tile = dn >> 8;
        int e = (dn & 255) * 2;
        int lane = e >> 3, j0 = e & 7;
        int quad = lane >> 4;
        int nt = tile / 7, tt = tile % 7;
        int col = nt * 16 + (lane & 15);
        float v0, v1;
        if (tt < 6) {
            const float* W = isS ? ((tt < 2) ? sWh : (tt < 4) ? sWa : sWb)
                                 : ((tt < 2) ? nWh : (tt < 4) ? nWa : nWb);
            int k = (tt & 1) * 32 + quad * 8 + j0;
            v0 = W[k * 256 + col]; v1 = W[(k + 1) * 256 + col];
        } else {
            int kl = quad * 8 + j0;
            auto xv = [&](int k) -> float {
                if (!isS) { if (k < 3) return nWx[k * 256 + col]; if (k == 3) return nb[col]; return 0.f; }
                else      { if (k == 4) return sWx[col]; if (k == 5) return sb[col]; return 0.f; }
            };
            v0 = xv(kl); v1 = xv(kl + 1);
        }
        wsu[(isS ? OFF_SPK : OFF_NPK) + dn] = pack2(v0, v1);
    } else {
        int dd = idx - 2 * NPK_DW;
        int tile = dd >> 8;
        int e = (dd & 255) * 2;
        int lane = e >> 3, j0 = e & 7;
        int quad = lane >> 4;
        int nt = tile >> 4, tt = tile & 15;
        const float* W = (tt < 4) ? dWx : (tt < 8) ? dWh : (tt < 12) ? dWa : dWb;
        int k = (tt & 3) * 32 + quad * 8 + j0;
        int col = nt * 16 + (lane & 15);
        wsu[OFF_DPK + dd] = pack2(W[k * 512 + col], W[(k + 1) * 512 + col]);
    }
}

// Pipelined launch li: blocks 0-127 run phase A of step t=li (n/s cells + dWx@dec
// gate partials); blocks 128-255 run phase B of step t=li-1 (dWh/dWa/dWb + epilogue
// + heads). All cross-role hand-offs are cross-launch (parity buffers).
__global__ __launch_bounds__(TB) void pipe_kernel(
    int li,
    const float* __restrict__ input,
    const float* __restrict__ db,
    const float* __restrict__ onW, const float* __restrict__ onb,
    const float* __restrict__ osW, const float* __restrict__ osb,
    float* __restrict__ ws)
{
    const int tid = threadIdx.x;
    const int wave = tid >> 6, lane = tid & 63;
    const int quad = lane >> 4, l15 = lane & 15;
    const int blk = blockIdx.x;

    _Float16* hnG = (_Float16*)((unsigned int*)ws + OFF_HN);
    _Float16* hsG = (_Float16*)((unsigned int*)ws + OFF_HS);
    _Float16* hdG = (_Float16*)((unsigned int*)ws + OFF_HD);
    float* cn = ws + OFF_CN;
    float* cs = ws + OFF_CS;
    float* cd = ws + OFF_CD;
    float* gpart = ws + OFF_GP;
    float* outs = ws + OFF_OUTS;
    const _Float16* pd = (const _Float16*)((const unsigned int*)ws + OFF_DPK);

    __shared__ __align__(16) _Float16 sh_hn[18 * 72];
    __shared__ __align__(16) _Float16 sh_hs[18 * 72];
    __shared__ __align__(16) _Float16 sh_xa[16 * 40];
    __shared__ __align__(16) _Float16 sh_dec[16 * 136];
    __shared__ __align__(16) _Float16 sh_hd[18 * 136];
    __shared__ float sh_hdnew[16 * 128];

    if (blk < 128) {
        // ================= A role: step t = li =================
        if (li > 126) return;
        const int ab = blk;
        const int r0 = ab * RPB;
        const int b = r0 >> 7;
        const int s0 = r0 & 127;
        const bool leftOK = (ab & 7) != 0;
        const bool rightOK = (ab & 7) != 7;
        const int pin = (li + 1) & 1, pout = li & 1;
        const _Float16* hnC = hnG + (size_t)pin * ROWS * 64;
        const _Float16* hsC = hsG + (size_t)pin * ROWS * 64;
        _Float16* hnN = hnG + (size_t)pout * ROWS * 64;
        _Float16* hsN = hsG + (size_t)pout * ROWS * 64;

        // stage hn/hs (+/-1 halo rows)
        for (int i = tid; i < 1152; i += TB) {
            bool isHs = i >= 576;
            int j = isHs ? i - 576 : i;
            int row = j >> 5, p = j & 31;
            int grow = r0 + row - 1;
            bool v = (row == 0) ? leftOK : ((row == 17) ? rightOK : true);
            const _Float16* src = isHs ? hsC : hnC;
            unsigned int val = v ? ((const unsigned int*)src)[(size_t)grow * 32 + p] : 0u;
            _Float16* dst = isHs ? sh_hs : sh_hn;
            *(unsigned int*)(dst + row * 72 + 2 * p) = val;
        }
        for (int i = tid; i < 272; i += TB) {
            int r = i / 17, d = 3 + (i % 17);
            ((unsigned int*)sh_xa)[r * 20 + d] = 0u;
        }
        if (tid < 16) {
            const float* xp = input + ((size_t)(b * T_ + li) * S_ + (s0 + tid)) * 4;
            unsigned int* row = (unsigned int*)sh_xa + tid * 20;
            row[0] = pack2(xp[0], xp[1]);
            row[1] = pack2(xp[2], 1.f);
            row[2] = pack2(xp[3], 1.f);
        }
        __syncthreads();

        // phase A MFMA: waves 0-3 n-cell, 4-7 s-cell (16-col sub per wave)
        {
            const int subA = wave & 3;
            const bool isS = (wave >= 4);
            const _Float16* hb = isS ? sh_hs : sh_hn;
            const _Float16* pk = (const _Float16*)((const unsigned int*)ws + (isS ? OFF_SPK : OFF_NPK));
            half8 ah0 = *(const half8*)(hb + (l15 + 1) * 72 + quad * 8);
            half8 ah1 = *(const half8*)(hb + (l15 + 1) * 72 + 32 + quad * 8);
            half8 aa0 = *(const half8*)(hb + (l15 + 2) * 72 + quad * 8);
            half8 aa1 = *(const half8*)(hb + (l15 + 2) * 72 + 32 + quad * 8);
            half8 ab0 = *(const half8*)(hb + (l15) * 72 + quad * 8);
            half8 ab1 = *(const half8*)(hb + (l15) * 72 + 32 + quad * 8);
            half8 ax  = *(const half8*)(sh_xa + l15 * 40 + quad * 8);
            float4v acc[4];
#pragma unroll
            for (int g = 0; g < 4; ++g) acc[g] = (float4v){0.f, 0.f, 0.f, 0.f};
#pragma unroll
            for (int g = 0; g < 4; ++g) {
                const _Float16* base = pk + (size_t)(4 * g + subA) * 7 * 512 + lane * 8;
                acc[g] = __builtin_amdgcn_mfma_f32_16x16x32_f16(ah0, *(const half8*)(base),        acc[g], 0, 0, 0);
                acc[g] = __builtin_amdgcn_mfma_f32_16x16x32_f16(ah1, *(const half8*)(base + 512),  acc[g], 0, 0, 0);
                acc[g] = __builtin_amdgcn_mfma_f32_16x16x32_f16(aa0, *(const half8*)(base + 1024), acc[g], 0, 0, 0);
                acc[g] = __builtin_amdgcn_mfma_f32_16x16x32_f16(aa1, *(const half8*)(base + 1536), acc[g], 0, 0, 0);
                acc[g] = __builtin_amdgcn_mfma_f32_16x16x32_f16(ab0, *(const half8*)(base + 2048), acc[g], 0, 0, 0);
                acc[g] = __builtin_amdgcn_mfma_f32_16x16x32_f16(ab1, *(const half8*)(base + 2560), acc[g], 0, 0, 0);
                acc[g] = __builtin_amdgcn_mfma_f32_16x16x32_f16(ax,  *(const half8*)(base + 3072), acc[g], 0, 0, 0);
            }
            float* cB = isS ? cs : cn;
            size_t cIdx = ((size_t)(ab * 4 + subA) * 64 + lane) * 4;
            float4v cold = *(const float4v*)(cB + cIdx);
            float4v cnew;
            _Float16* hN = isS ? hsN : hnN;
            const int kcol = 16 * subA + l15;
#pragma unroll
            for (int r = 0; r < 4; ++r) {
                float c2 = sigm(acc[1][r]) * cold[r] + sigm(acc[0][r]) * tanh_(acc[2][r]);
                float h2 = sigm(acc[3][r]) * tanh_(c2);
                cnew[r] = c2;
                int row = quad * 4 + r;
                hN[(size_t)(r0 + row) * 64 + kcol] = (_Float16)h2;
                sh_dec[row * 136 + (isS ? 64 : 0) + kcol] = (_Float16)h2;
            }
            *(float4v*)(cB + cIdx) = cnew;
        }
        __syncthreads();

        // dWx @ dec gate partials (all 8 waves; ct = wave covers 128 d-cols)
        {
            const int ct = wave;
            half8 aD[4];
#pragma unroll
            for (int kt = 0; kt < 4; ++kt)
                aD[kt] = *(const half8*)(sh_dec + l15 * 136 + kt * 32 + quad * 8);
            float4v accP[4];
#pragma unroll
            for (int g = 0; g < 4; ++g) accP[g] = (float4v){0.f, 0.f, 0.f, 0.f};
#pragma unroll
            for (int g = 0; g < 4; ++g) {
                const _Float16* base = pd + (size_t)(g * 8 + ct) * 16 * 512 + lane * 8;
#pragma unroll
                for (int kt = 0; kt < 4; ++kt)
                    accP[g] = __builtin_amdgcn_mfma_f32_16x16x32_f16(aD[kt], *(const half8*)(base + kt * 512), accP[g], 0, 0, 0);
            }
            float* gp = gpart + ((((size_t)(li & 1) * 128 + ab) * 8 + ct) * 4) * 256;
#pragma unroll
            for (int g = 0; g < 4; ++g)
                *(float4v*)&gp[g * 256 + lane * 4] = accP[g];
        }
    } else {
        // ================= B role: step t = li-1 =================
        if (li < 1) return;
        const int bb = blk - 128;
        const int t = li - 1;
        const int r0 = bb * RPB;
        const bool leftOK = (bb & 7) != 0;
        const bool rightOK = (bb & 7) != 7;
        const int pinD = li & 1;           // hd(t-1) parity
        const int poutD = (li + 1) & 1;    // hd(t) parity
        const _Float16* hdC = hdG + (size_t)pinD * ROWS * 128;
        _Float16* hdN = hdG + (size_t)poutD * ROWS * 128;

        for (int i = tid; i < 1152; i += TB) {
            int row = i >> 6, p = i & 63;
            int grow = r0 + row - 1;
            bool v = (row == 0) ? leftOK : ((row == 17) ? rightOK : true);
            unsigned int val = v ? ((const unsigned int*)hdC)[(size_t)grow * 64 + p] : 0u;
            *(unsigned int*)(sh_hd + row * 136 + 2 * p) = val;
        }
        __syncthreads();

        {
            const int ct = wave;
            // init acc from A's dWx partials (written last launch)
            const float* gp = gpart + ((((size_t)((li + 1) & 1) * 128 + bb) * 8 + ct) * 4) * 256;
            float4v acc[4];
#pragma unroll
            for (int g = 0; g < 4; ++g) acc[g] = *(const float4v*)&gp[g * 256 + lane * 4];
            half8 aH[4], aA[4], aB4[4];
#pragma unroll
            for (int kt = 0; kt < 4; ++kt) {
                aH[kt]  = *(const half8*)(sh_hd + (l15 + 1) * 136 + kt * 32 + quad * 8);
                aA[kt]  = *(const half8*)(sh_hd + (l15 + 2) * 136 + kt * 32 + quad * 8);
                aB4[kt] = *(const half8*)(sh_hd + (l15) * 136 + kt * 32 + quad * 8);
            }
#pragma unroll
            for (int g = 0; g < 4; ++g) {
                const _Float16* base = pd + (size_t)(g * 8 + ct) * 16 * 512 + lane * 8;
#pragma unroll
                for (int kt = 0; kt < 4; ++kt)
                    acc[g] = __builtin_amdgcn_mfma_f32_16x16x32_f16(aH[kt], *(const half8*)(base + (4 + kt) * 512), acc[g], 0, 0, 0);
#pragma unroll
                for (int kt = 0; kt < 4; ++kt)
                    acc[g] = __builtin_amdgcn_mfma_f32_16x16x32_f16(aA[kt], *(const half8*)(base + (8 + kt) * 512), acc[g], 0, 0, 0);
#pragma unroll
                for (int kt = 0; kt < 4; ++kt)
                    acc[g] = __builtin_amdgcn_mfma_f32_16x16x32_f16(aB4[kt], *(const half8*)(base + (12 + kt) * 512), acc[g], 0, 0, 0);
            }
            const int kd = 16 * ct + l15;
            float bi = db[kd], bf = db[128 + kd], bu = db[256 + kd], bo = db[384 + kd];
            float* cPtr = cd + ((size_t)(bb * 8 + ct) * 64 + lane) * 4;
            float4v cold = *(float4v*)cPtr, cnew;
#pragma unroll
            for (int r = 0; r < 4; ++r) {
                float c2 = sigm(acc[1][r] + bf) * cold[r] + sigm(acc[0][r] + bi) * tanh_(acc[2][r] + bu);
                float h2 = sigm(acc[3][r] + bo) * tanh_(c2);
                cnew[r] = c2;
                int row = quad * 4 + r;
                hdN[(size_t)(r0 + row) * 128 + kd] = (_Float16)h2;
                sh_hdnew[row * 128 + kd] = h2;
            }
            *(float4v*)cPtr = cnew;
        }
        __syncthreads();

        // output heads for step t
        {
            int p = tid >> 4, l16 = tid & 15;
            int row = p >> 1, head = p & 1;
            const float* W = head ? osW : onW;
            float partial = 0.f;
#pragma unroll
            for (int k = 0; k < 128; k += 16) partial += sh_hdnew[row * 128 + k + l16] * W[k + l16];
#pragma unroll
            for (int off = 8; off; off >>= 1) partial += __shfl_down(partial, off, 16);
            if (l16 == 0)
                outs[((size_t)t * ROWS + (r0 + row)) * 2 + head] = partial + (head ? osb[0] : onb[0]);
        }
    }
}

// Assemble data outputs for t in [20,126] (head biases already in outs).
__global__ __launch_bounds__(256) void assemble_kernel(
    const float* __restrict__ input, const float* __restrict__ ws, float* __restrict__ out)
{
    const float* outs = ws + OFF_OUTS;
    int idx = blockIdx.x * 256 + threadIdx.x;  // (b, tt, s)
    if (idx >= B_ * TOUT * S_) return;
    int s = idx & 127;
    int tmp = idx >> 7;
    int tt = tmp % TOUT;
    int b = tmp / TOUT;
    int t = tt + TPRED;
    int row = b * S_ + s;
    float o0 = outs[((size_t)t * ROWS + row) * 2 + 0];
    float o1 = outs[((size_t)t * ROWS + row) * 2 + 1];
    float inflow = (s == 0) ? input[(((size_t)b * T_ + (t + 1)) * S_ + 0) * 4 + 1]
                            : outs[((size_t)t * ROWS + row - 1) * 2 + 0];
    float numc = input[(((size_t)b * T_ + t) * S_ + s) * 4 + 2] + inflow - o0;
    float spd = (s == 0) ? input[(((size_t)b * T_ + (t + 1)) * S_ + 0) * 4 + 3] : o1;
    float4 v = make_float4(o0, inflow, numc, spd);
    reinterpret_cast<float4*>(out)[idx] = v;
}

extern "C" void kernel_launch(void* const* d_in, const int* in_sizes, int n_in,
                              void* d_out, int out_size, void* d_ws, size_t ws_size,
                              hipStream_t stream) {
    const float* input = (const float*)d_in[0];
    const float* nWx = (const float*)d_in[1];
    const float* nWh = (const float*)d_in[2];
    const float* nWa = (const float*)d_in[3];
    const float* nWb = (const float*)d_in[4];
    const float* nb  = (const float*)d_in[5];
    const float* sWx = (const float*)d_in[6];
    const float* sWh = (const float*)d_in[7];
    const float* sWa = (const float*)d_in[8];
    const float* sWb = (const float*)d_in[9];
    const float* sb  = (const float*)d_in[10];
    const float* dWx = (const float*)d_in[11];
    const float* dWh = (const float*)d_in[12];
    const float* dWa = (const float*)d_in[13];
    const float* dWb = (const float*)d_in[14];
    const float* db  = (const float*)d_in[15];
    const float* onW = (const float*)d_in[16];
    const float* onb = (const float*)d_in[17];
    const float* osW = (const float*)d_in[18];
    const float* osb = (const float*)d_in[19];

    float* ws = (float*)d_ws;

    // zero h (both parities) + c; gpart/outs are written before read
    hipMemsetAsync(ws, 0, (size_t)ZERO_DW * 4, stream);

    // pack weights into MFMA B-fragment tiles (once per call)
    pack_weights<<<dim3((PACK_DWORDS + 255) / 256), dim3(256), 0, stream>>>(
        nWx, nWh, nWa, nWb, nb, sWx, sWh, sWa, sWb, sb,
        dWx, dWh, dWa, dWb, (unsigned int*)ws);

    // pipelined launches: li=0 (A only) .. li=127 (B only)
    for (int li = 0; li <= NSTEPS; ++li) {
        pipe_kernel<<<dim3(NBLK), dim3(TB), 0, stream>>>(
            li, input, db, onW, onb, osW, osb, ws);
    }

    int nout = B_ * TOUT * S_;
    assemble_kernel<<<dim3((nout + 255) / 256), dim3(256), 0, stream>>>(input, ws, (float*)d_out);
}